// Round 1
// baseline (32862.387 us; speedup 1.0000x reference)
//
#include <hip/hip_runtime.h>
#include <hip/hip_bf16.h>
#include <math.h>

#define T_STEPS 4096
#define IN_DIM  512
#define HID     2048
#define LEAK    0.3f

// ---------------------------------------------------------------------------
// Phase 1: P = U @ Win^T + bias, written directly into d_out (T x HID, f32)
// ---------------------------------------------------------------------------
#define GBM 64
#define GBN 64
#define GBK 32

__global__ __launch_bounds__(256) void gemm_p(const float* __restrict__ U,
                                              const float* __restrict__ Win,
                                              const float* __restrict__ bias,
                                              float* __restrict__ P) {
  __shared__ float As[GBM][GBK + 1];
  __shared__ float Bs[GBN][GBK + 1];
  const int bm = blockIdx.x, bn = blockIdx.y;
  const int tid = threadIdx.x;
  const int tx = tid & 15, ty = tid >> 4;

  float acc[4][4];
#pragma unroll
  for (int m = 0; m < 4; ++m)
#pragma unroll
    for (int n = 0; n < 4; ++n) acc[m][n] = 0.f;

  const float* Ub = U + (size_t)bm * GBM * IN_DIM;
  const float* Wb = Win + (size_t)bn * GBN * IN_DIM;

  for (int k0 = 0; k0 < IN_DIM; k0 += GBK) {
    // stage 64x32 A tile (U rows) and 64x32 B tile (Win rows)
#pragma unroll
    for (int v = 0; v < 2; ++v) {
      const int f4 = v * 256 + tid;
      const int row = f4 >> 3;          // 8 float4 per row of 32 floats
      const int c4 = (f4 & 7) << 2;
      const float4 a = *(const float4*)(Ub + (size_t)row * IN_DIM + k0 + c4);
      As[row][c4 + 0] = a.x; As[row][c4 + 1] = a.y;
      As[row][c4 + 2] = a.z; As[row][c4 + 3] = a.w;
      const float4 b = *(const float4*)(Wb + (size_t)row * IN_DIM + k0 + c4);
      Bs[row][c4 + 0] = b.x; Bs[row][c4 + 1] = b.y;
      Bs[row][c4 + 2] = b.z; Bs[row][c4 + 3] = b.w;
    }
    __syncthreads();
#pragma unroll 8
    for (int k = 0; k < GBK; ++k) {
      float a[4], b[4];
#pragma unroll
      for (int m = 0; m < 4; ++m) a[m] = As[ty * 4 + m][k];
#pragma unroll
      for (int n = 0; n < 4; ++n) b[n] = Bs[tx * 4 + n][k];
#pragma unroll
      for (int m = 0; m < 4; ++m)
#pragma unroll
        for (int n = 0; n < 4; ++n)
          acc[m][n] = fmaf(a[m], b[n], acc[m][n]);
    }
    __syncthreads();
  }

#pragma unroll
  for (int m = 0; m < 4; ++m) {
    const int gr = bm * GBM + ty * 4 + m;
#pragma unroll
    for (int n = 0; n < 4; ++n) {
      const int gc = bn * GBN + tx * 4 + n;
      P[(size_t)gr * HID + gc] = acc[m][n] + bias[gc];
    }
  }
}

// ---------------------------------------------------------------------------
// Phase 2: persistent recurrence. 128 blocks x 256 threads.
// Each block owns 16 rows; 16 threads/row; each thread holds 32 float4 of W
// in registers for the whole kernel. Step t: read h_{t-1} = out[t-1][:],
// P_t = out[t][own rows], write h_t over out[t][own rows]. Grid barrier
// between steps (monotonic counter in d_ws).
// ---------------------------------------------------------------------------
#define NB   128                 // blocks
#define NT   256                 // threads per block
#define RPB  (HID / NB)          // 16 rows per block
#define TPR  (NT / RPB)          // 16 threads per row
#define NF4  (HID / (TPR * 4))   // 32 float4 chunks per thread

__device__ __forceinline__ float fast_tanh(float x) {
  // tanh(x) = 1 - 2/(exp(2x)+1); exact saturation at +-inf
  const float e = __expf(2.f * x);
  return 1.f - 2.f / (e + 1.f);
}

__device__ __forceinline__ void grid_bar(unsigned* cnt, unsigned target) {
  __syncthreads();                      // drains each wave's stores to L2
  if (threadIdx.x == 0) {
    // release: wbl2 (whole XCD L2 incl. other waves' lines) -> LLC, then add
    __hip_atomic_fetch_add(cnt, 1u, __ATOMIC_RELEASE, __HIP_MEMORY_SCOPE_AGENT);
    while (__hip_atomic_load(cnt, __ATOMIC_RELAXED, __HIP_MEMORY_SCOPE_AGENT) < target) {
      __builtin_amdgcn_s_sleep(1);
    }
    __threadfence();                    // acquire: invalidate L1/L2 so fresh h is read
  }
  __syncthreads();
}

__global__ __launch_bounds__(NT, 1) void esn_recur(const float* __restrict__ W,
                                                   float* __restrict__ out,
                                                   unsigned* __restrict__ cnt) {
  const int tid = threadIdx.x;
  const int j   = tid & (TPR - 1);       // lane within row
  const int rl  = tid >> 4;              // local row (log2(TPR)=4)
  const int row = blockIdx.x * RPB + rl;

  // Pin this thread's W fragment in registers: W[row][j*4 + i*64 .. +3]
  float4 wreg[NF4];
  const float4* wrow = (const float4*)(W + (size_t)row * HID);
#pragma unroll
  for (int i = 0; i < NF4; ++i) wreg[i] = wrow[i * TPR + j];

  // t = 0: h0 = leak * tanh(P0)   (h_{-1} = 0)
  {
    const float pre = out[row];
    const float h = LEAK * fast_tanh(pre);
    if (j == 0) out[row] = h;
  }
  unsigned target = NB;
  grid_bar(cnt, target);

  for (int t = 1; t < T_STEPS; ++t) {
    const float* __restrict__ hprev = out + (size_t)(t - 1) * HID;
    float* __restrict__ ocur = out + (size_t)t * HID;

    const float p  = ocur[row];    // P_t[row]  (broadcast across the 16 lanes)
    const float hp = hprev[row];   // h_{t-1}[row]

    float4 acc = make_float4(0.f, 0.f, 0.f, 0.f);
#pragma unroll
    for (int i = 0; i < NF4; ++i) {
      const float4 hv = *(const float4*)(hprev + i * (TPR * 4) + j * 4);
      acc.x = fmaf(wreg[i].x, hv.x, acc.x);
      acc.y = fmaf(wreg[i].y, hv.y, acc.y);
      acc.z = fmaf(wreg[i].z, hv.z, acc.z);
      acc.w = fmaf(wreg[i].w, hv.w, acc.w);
    }
    float a = (acc.x + acc.y) + (acc.z + acc.w);
    a += __shfl_xor(a, 1, TPR);
    a += __shfl_xor(a, 2, TPR);
    a += __shfl_xor(a, 4, TPR);
    a += __shfl_xor(a, 8, TPR);

    const float pre = p + a;
    const float h = (1.f - LEAK) * hp + LEAK * fast_tanh(pre);
    if (j == 0) ocur[row] = h;

    target += NB;
    grid_bar(cnt, target);
  }
}

// ---------------------------------------------------------------------------
extern "C" void kernel_launch(void* const* d_in, const int* in_sizes, int n_in,
                              void* d_out, int out_size, void* d_ws, size_t ws_size,
                              hipStream_t stream) {
  const float* U    = (const float*)d_in[0];
  const float* Win  = (const float*)d_in[1];
  const float* W    = (const float*)d_in[2];
  const float* bias = (const float*)d_in[3];
  float* out = (float*)d_out;
  unsigned* cnt = (unsigned*)d_ws;

  hipMemsetAsync(d_ws, 0, 256, stream);

  dim3 ggrid(T_STEPS / GBM, HID / GBN);
  gemm_p<<<ggrid, 256, 0, stream>>>(U, Win, bias, out);

  esn_recur<<<NB, NT, 0, stream>>>(W, out, cnt);
}